// Round 2
// baseline (43737.875 us; speedup 1.0000x reference)
//
#include <hip/hip_runtime.h>
#include <hip/hip_cooperative_groups.h>
#include <cstdint>
#include <cstddef>

namespace cg = cooperative_groups;

#define L_ 128
#define B_ 32
#define E_ 512
#define H_ 512
#define H2_ 1024
#define V_ 32000
#define SOS_ 65
#define NBLK 256

typedef __attribute__((ext_vector_type(8))) short bf8;
typedef __attribute__((ext_vector_type(4))) float f4;

__device__ __forceinline__ short bf1(float x){
  union { float f; unsigned u; } c; c.f = x;
  return (short)((c.u + 0x8000u) >> 16);
}
__device__ __forceinline__ unsigned short f2b(float x){
  union { float f; unsigned u; } c; c.f = x;
  return (unsigned short)((c.u + 0x8000u) >> 16);
}
__device__ __forceinline__ float b2f(unsigned short u){
  union { unsigned u; float f; } c; c.u = ((unsigned)u) << 16; return c.f;
}
__device__ __forceinline__ bf8 fragf(const float* p){
  f4 a = ((const f4*)p)[0], b = ((const f4*)p)[1];
  bf8 r;
  r[0]=bf1(a[0]); r[1]=bf1(a[1]); r[2]=bf1(a[2]); r[3]=bf1(a[3]);
  r[4]=bf1(b[0]); r[5]=bf1(b[1]); r[6]=bf1(b[2]); r[7]=bf1(b[3]);
  return r;
}
__device__ __forceinline__ float sigf(float x){ return 1.0f/(1.0f + __expf(-x)); }
__device__ __forceinline__ float tanh_(float x){ return 1.0f - 2.0f/(__expf(2.0f*x)+1.0f); }
__device__ __forceinline__ f4 mfma16(bf8 a, bf8 b, f4 c){
  return __builtin_amdgcn_mfma_f32_16x16x32_bf16(a, b, c, 0, 0, 0);
}
__device__ __forceinline__ void comb3(float& M, float& S, int& I,
                                      float m2, float s2, int i2){
  if (m2 > M) { S = s2 + S*__expf(M - m2); M = m2; I = i2; }
  else { S += s2*__expf(m2 - M); if (m2 == M && i2 < I) I = i2; }
}

struct MP {
  const int *x, *target;
  const float *emb_enc, *Wih_f, *Whh_f, *bih_f, *bhh_f;
  const float *Wih_b, *Whh_b, *bih_b, *bhh_b;
  const float *emb_dec, *W_attn, *b_attn, *W_comb, *b_comb;
  const float *Wih_d, *Whh_d, *bih_d, *bhh_d, *W_out, *b_out;
  unsigned short *h_enc;    // [2 parity][2 dir][32][512] bf16
  unsigned short *h_d;      // [32][1024] bf16
  float *EO;                // [128][1024] f32
  unsigned short *ctxb;     // [32][1024] bf16
  unsigned short *comb;     // [32][1024] bf16
  float *pmax, *psum; int *pidx;  // [500][32]
  float *ptgt; float *loss; int *inp;
  float *benc;              // [2][2048]
  float *bdec;              // [4096]
  unsigned short *Wencb;    // [2][2048][1024]  (k<512: Wih, k>=512: Whh)
  unsigned short *Whhdb;    // [4096][1024]
  unsigned short *Wihdb;    // [4096][1024]
  unsigned short *Wcombb;   // [1024][2048]
  unsigned short *Woutb;    // [32000][1024]
  float *out;
};

template<bool PK>
__global__ __launch_bounds__(256) void mega(MP p)
{
  cg::grid_group gg = cg::this_grid();
  const int blk = blockIdx.x, tid = threadIdx.x;
  const int wave = tid >> 6, lane = tid & 63;
  const int q = lane >> 4, cl = lane & 15;

  __shared__ float Carr[512];     // block-persistent LSTM cell state
  __shared__ float scr[2208];     // stage scratch (Lg / X+sc+red / lmax..)

  // ================= init + pack phase =================
  {
    const int g0 = blk*256 + tid;          // 0..65535
    if (g0 < 32768) ((unsigned*)p.h_enc)[g0] = 0u;
    if (g0 < 16384) ((unsigned*)p.h_d)[g0] = 0u;
    if (g0 == 0) *p.loss = 0.f;
    if (g0 < 2048) {
      p.benc[g0]        = p.bih_f[g0] + p.bhh_f[g0];
      p.benc[2048 + g0] = p.bih_b[g0] + p.bhh_b[g0];
    }
    if (g0 < 4096) p.bdec[g0] = p.bih_d[g0] + p.bhh_d[g0];
    if (PK) {
      for (int i = g0; i < 2*2048*128; i += 65536) {     // Wenc combined [e|h]
        const int dir = i >> 18;
        const int r   = i & ((1<<18)-1);
        const int n   = r >> 7, k = (r & 127) * 8;
        const float* src = (k < 512)
          ? ((dir ? p.Wih_b : p.Wih_f) + (size_t)n*512 + k)
          : ((dir ? p.Whh_b : p.Whh_f) + (size_t)n*512 + (k - 512));
        ((bf8*)p.Wencb)[i] = fragf(src);
      }
      for (int i = g0; i < 4096*128; i += 65536)
        ((bf8*)p.Whhdb)[i] = fragf(p.Whh_d + (size_t)i*8);
      for (int i = g0; i < 4096*128; i += 65536)
        ((bf8*)p.Wihdb)[i] = fragf(p.Wih_d + (size_t)i*8);
      for (int i = g0; i < 1024*256; i += 65536)
        ((bf8*)p.Wcombb)[i] = fragf(p.W_comb + (size_t)i*8);
      for (int i = g0; i < 32000*128; i += 65536)
        ((bf8*)p.Woutb)[i] = fragf(p.W_out + (size_t)i*8);
    }
  }
  gg.sync();

  // ================= encoder: 1 grid sync / step =================
  for (int t = 0; t < L_; ++t) {
    if (blk < 64) {
      const int dir = blk >> 5, jb = blk & 31;
      const int n = wave*512 + jb*16 + cl;   // row: gate=wave, j=jb*16+cl
      const unsigned short* hprev = p.h_enc + ((size_t)((t&1)*2 + dir))*B_*512;
      unsigned short* hnext = p.h_enc + ((size_t)(((t+1)&1)*2 + dir))*B_*512;
      const unsigned short* wrow = p.Wencb + ((size_t)(dir*2048 + n) << 10);
      const float* wih = (dir ? p.Wih_b : p.Wih_f) + (size_t)n*512;
      const float* whh = (dir ? p.Whh_b : p.Whh_f) + (size_t)n*512;
      const float* e0 = p.emb_enc + (size_t)p.x[cl*L_ + t]*E_ + q*8;
      const float* e1 = p.emb_enc + (size_t)p.x[(16+cl)*L_ + t]*E_ + q*8;
      f4 a0 = {0.f,0.f,0.f,0.f}, a1 = {0.f,0.f,0.f,0.f};
#pragma unroll 4
      for (int i = 0; i < 16; ++i) {
        const int k = i*32 + q*8;
        bf8 bb = PK ? *(const bf8*)(wrow + k) : fragf(wih + k);
        a0 = mfma16(fragf(e0 + i*32), bb, a0);
        a1 = mfma16(fragf(e1 + i*32), bb, a1);
      }
#pragma unroll 4
      for (int i = 0; i < 16; ++i) {
        const int k = i*32 + q*8;
        bf8 bb = PK ? *(const bf8*)(wrow + 512 + k) : fragf(whh + k);
        a0 = mfma16(*(const bf8*)(hprev + (size_t)cl*512 + k), bb, a0);
        a1 = mfma16(*(const bf8*)(hprev + (size_t)(16+cl)*512 + k), bb, a1);
      }
      const float bias = p.benc[dir*2048 + n];
      if (t == 0) { Carr[tid] = 0.f; Carr[256 + tid] = 0.f; }
#pragma unroll
      for (int r = 0; r < 4; ++r) {
        scr[(wave*32 + 4*q + r)*16 + cl]      = a0[r] + bias;
        scr[(wave*32 + 16 + 4*q + r)*16 + cl] = a1[r] + bias;
      }
      __syncthreads();
      for (int u = tid; u < 512; u += 256) {
        const int b = u >> 4, cc = u & 15;
        const float gi = scr[(0*32+b)*16+cc], gf = scr[(1*32+b)*16+cc];
        const float gv = scr[(2*32+b)*16+cc], go = scr[(3*32+b)*16+cc];
        const float cp = Carr[u];
        const float cn = sigf(gf)*cp + sigf(gi)*tanh_(gv);
        const float hn = sigf(go)*tanh_(cn);
        Carr[u] = cn;
        hnext[(size_t)b*512 + jb*16 + cc] = f2b(hn);
        if (b == 0) p.EO[(size_t)t*H2_ + dir*512 + jb*16 + cc] = hn;  // source-bug broadcast
      }
    }
    gg.sync();
  }

  // ================= decoder: 4 grid syncs / step =================
  for (int t = 0; t < L_; ++t) {
    f4 g0a = {0.f,0.f,0.f,0.f}, g1a = {0.f,0.f,0.f,0.f};
    // ---------- stage A: attn (+prev-step reduce) || gates_hh ----------
    if (blk < 32) {
      float* X   = scr;            // 2048
      float* sc  = scr + 2048;     // 128
      float* red = scr + 2176;     // 16
      int*   ib  = (int*)(scr + 2200);
      int myinp;
      if (t > 0) {
        float M = -3.4e38f, S = 0.f; int I = 0x7fffffff;
        for (int tl = tid; tl < 500; tl += 256)
          comb3(M, S, I, p.pmax[tl*32 + blk], p.psum[tl*32 + blk], p.pidx[tl*32 + blk]);
#pragma unroll
        for (int m = 1; m < 64; m <<= 1) {
          const float m2 = __shfl_xor(M, m), s2 = __shfl_xor(S, m);
          const int i2 = __shfl_xor(I, m);
          comb3(M, S, I, m2, s2, i2);
        }
        if (lane == 0) { red[wave] = M; red[4+wave] = S; ((int*)(red+8))[wave] = I; }
        __syncthreads();
        if (tid == 0) {
          M = red[0]; S = red[4]; I = ((int*)(red+8))[0];
          for (int w = 1; w < 4; ++w) comb3(M, S, I, red[w], red[4+w], ((int*)(red+8))[w]);
          atomicAdd(p.loss, (M + __logf(S) - p.ptgt[blk]) * (1.0f/32.0f));
          p.inp[blk] = I;
          *ib = I;
        }
        __syncthreads();
        myinp = *ib;
      } else {
        myinp = SOS_;
        if (tid == 0) p.inp[blk] = SOS_;
      }
      // attention for batch row blk
      {
        const float* e = p.emb_dec + (size_t)myinp*H2_;
        ((f4*)X)[tid] = ((const f4*)e)[tid];
        const unsigned short* hb = p.h_d + (size_t)blk*H2_ + tid*4;
        X[1024 + tid*4 + 0] = b2f(hb[0]);
        X[1024 + tid*4 + 1] = b2f(hb[1]);
        X[1024 + tid*4 + 2] = b2f(hb[2]);
        X[1024 + tid*4 + 3] = b2f(hb[3]);
      }
      __syncthreads();
      const int lg = tid >> 4, kl = tid & 15;
#pragma unroll
      for (int lr = 0; lr < 8; ++lr) {
        const int l = lr*16 + lg;
        const float* w = p.W_attn + (size_t)l*2048;
        float s = 0.f;
        for (int kk = kl*4; kk < 2048; kk += 64) {
          const f4 wv = *(const f4*)(w + kk);
          const f4 xv = *(const f4*)(X + kk);
          s += wv[0]*xv[0] + wv[1]*xv[1] + wv[2]*xv[2] + wv[3]*xv[3];
        }
#pragma unroll
        for (int m = 1; m < 16; m <<= 1) s += __shfl_xor(s, m);
        if (kl == 0) sc[l] = s + p.b_attn[l];
      }
      __syncthreads();
      const float v = sc[tid & 127];
      float m_ = v;
#pragma unroll
      for (int m = 1; m < 64; m <<= 1) m_ = fmaxf(m_, __shfl_xor(m_, m));
      if (lane == 0) red[wave] = m_;
      __syncthreads();
      const float M2 = fmaxf(fmaxf(red[0], red[1]), fmaxf(red[2], red[3]));
      const float e_ = __expf(v - M2);
      float s_ = e_;
#pragma unroll
      for (int m = 1; m < 64; m <<= 1) s_ += __shfl_xor(s_, m);
      if (lane == 0) red[4 + wave] = s_;
      __syncthreads();
      const float Ssum = red[4] + red[5];   // waves 0,1 cover all 128 scores
      if (tid < 128) sc[tid] = e_ / Ssum;
      __syncthreads();
      const int d0 = tid*4;
      f4 a = {0.f,0.f,0.f,0.f};
      for (int l = 0; l < 128; ++l) {
        const float wgt = sc[l];
        const f4 ev = *(const f4*)(p.EO + (size_t)l*H2_ + d0);
        a[0] += wgt*ev[0]; a[1] += wgt*ev[1]; a[2] += wgt*ev[2]; a[3] += wgt*ev[3];
      }
      unsigned short* cb = p.ctxb + (size_t)blk*H2_ + d0;
      cb[0] = f2b(a[0]); cb[1] = f2b(a[1]); cb[2] = f2b(a[2]); cb[3] = f2b(a[3]);
    } else if (blk < 96) {
      const int jb = blk - 32;
      const int n = wave*1024 + jb*16 + cl;
      const unsigned short* wrow = p.Whhdb + ((size_t)n << 10);
      const float* wrf = p.Whh_d + ((size_t)n << 10);
#pragma unroll 4
      for (int i = 0; i < 32; ++i) {
        const int k = i*32 + q*8;
        bf8 bb = PK ? *(const bf8*)(wrow + k) : fragf(wrf + k);
        g0a = mfma16(*(const bf8*)(p.h_d + (size_t)cl*H2_ + k), bb, g0a);
        g1a = mfma16(*(const bf8*)(p.h_d + (size_t)(16+cl)*H2_ + k), bb, g1a);
      }
    }
    gg.sync();
    // ---------- stage B: comb ----------
    if (blk < 16) {
      const int n = blk*64 + wave*16 + cl;
      const unsigned short* wrow = p.Wcombb + ((size_t)n << 11);
      const float* wrf = p.W_comb + ((size_t)n << 11);
      const float* e0 = p.emb_dec + (size_t)p.inp[cl]*H2_;
      const float* e1 = p.emb_dec + (size_t)p.inp[16+cl]*H2_;
      f4 c0 = {0.f,0.f,0.f,0.f}, c1 = {0.f,0.f,0.f,0.f};
#pragma unroll 4
      for (int i = 0; i < 32; ++i) {
        const int k = i*32 + q*8;
        bf8 bb = PK ? *(const bf8*)(wrow + k) : fragf(wrf + k);
        c0 = mfma16(fragf(e0 + k), bb, c0);
        c1 = mfma16(fragf(e1 + k), bb, c1);
      }
#pragma unroll 4
      for (int i = 0; i < 32; ++i) {
        const int k = i*32 + q*8;
        bf8 bb = PK ? *(const bf8*)(wrow + 1024 + k) : fragf(wrf + 1024 + k);
        c0 = mfma16(*(const bf8*)(p.ctxb + (size_t)cl*H2_ + k), bb, c0);
        c1 = mfma16(*(const bf8*)(p.ctxb + (size_t)(16+cl)*H2_ + k), bb, c1);
      }
      const float bias = p.b_comb[n];
#pragma unroll
      for (int r = 0; r < 4; ++r) {
        p.comb[(size_t)(4*q + r)*H2_ + n]      = f2b(fmaxf(c0[r] + bias, 0.f));
        p.comb[(size_t)(16 + 4*q + r)*H2_ + n] = f2b(fmaxf(c1[r] + bias, 0.f));
      }
    }
    gg.sync();
    // ---------- stage C: gates_ih + cell ----------
    if (blk >= 32 && blk < 96) {
      const int jb = blk - 32;
      const int n = wave*1024 + jb*16 + cl;
      const unsigned short* wrow = p.Wihdb + ((size_t)n << 10);
      const float* wrf = p.Wih_d + ((size_t)n << 10);
#pragma unroll 4
      for (int i = 0; i < 32; ++i) {
        const int k = i*32 + q*8;
        bf8 bb = PK ? *(const bf8*)(wrow + k) : fragf(wrf + k);
        g0a = mfma16(*(const bf8*)(p.comb + (size_t)cl*H2_ + k), bb, g0a);
        g1a = mfma16(*(const bf8*)(p.comb + (size_t)(16+cl)*H2_ + k), bb, g1a);
      }
      const float bias = p.bdec[n];
      if (t == 0) { Carr[tid] = 0.f; Carr[256 + tid] = 0.f; }
#pragma unroll
      for (int r = 0; r < 4; ++r) {
        scr[(wave*32 + 4*q + r)*16 + cl]      = g0a[r] + bias;
        scr[(wave*32 + 16 + 4*q + r)*16 + cl] = g1a[r] + bias;
      }
      __syncthreads();
      for (int u = tid; u < 512; u += 256) {
        const int b = u >> 4, cc = u & 15;
        const float gi = scr[(0*32+b)*16+cc], gf = scr[(1*32+b)*16+cc];
        const float gv = scr[(2*32+b)*16+cc], go = scr[(3*32+b)*16+cc];
        const float cp = Carr[u];
        const float cn = sigf(gf)*cp + sigf(gi)*tanh_(gv);
        const float hn = sigf(go)*tanh_(cn);
        Carr[u] = cn;
        p.h_d[(size_t)b*H2_ + jb*16 + cc] = f2b(hn);
      }
    }
    gg.sync();
    // ---------- stage D: logits + per-tile partial softmax/argmax ----------
#pragma unroll 1
    for (int tt = 0; tt < 2; ++tt) {
      const int tile = blk + tt*256;
      if (tile < 500) {
        const int n = tile*64 + wave*16 + cl;
        const unsigned short* wrow = p.Woutb + ((size_t)n << 10);
        const float* wrf = p.W_out + ((size_t)n << 10);
        f4 A0 = {0.f,0.f,0.f,0.f}, A1 = {0.f,0.f,0.f,0.f};
#pragma unroll 8
        for (int i = 0; i < 32; ++i) {
          const int k = i*32 + q*8;
          bf8 bb = PK ? *(const bf8*)(wrow + k) : fragf(wrf + k);
          A0 = mfma16(*(const bf8*)(p.h_d + (size_t)cl*H2_ + k), bb, A0);
          A1 = mfma16(*(const bf8*)(p.h_d + (size_t)(16+cl)*H2_ + k), bb, A1);
        }
        const float bias = p.b_out[n];
        float* lmax = scr; float* lsum = scr + 128; int* lidx = (int*)(scr + 256);
#pragma unroll
        for (int mt = 0; mt < 2; ++mt) {
          const f4 av = mt ? A1 : A0;
          float val[4], mv[4]; int mi[4];
#pragma unroll
          for (int r = 0; r < 4; ++r) {
            val[r] = av[r] + bias;
            const int b_ = mt*16 + 4*q + r;
            if (p.target[b_*L_ + t] == n) p.ptgt[b_] = val[r];
            mv[r] = val[r]; mi[r] = n;
          }
#pragma unroll
          for (int m = 1; m < 16; m <<= 1) {
#pragma unroll
            for (int r = 0; r < 4; ++r) {
              const float ov = __shfl_xor(mv[r], m);
              const int oi = __shfl_xor(mi[r], m);
              if (ov > mv[r] || (ov == mv[r] && oi < mi[r])) { mv[r] = ov; mi[r] = oi; }
            }
          }
          float sv[4];
#pragma unroll
          for (int r = 0; r < 4; ++r) sv[r] = __expf(val[r] - mv[r]);
#pragma unroll
          for (int m = 1; m < 16; m <<= 1) {
#pragma unroll
            for (int r = 0; r < 4; ++r) sv[r] += __shfl_xor(sv[r], m);
          }
          if (cl == 0) {
#pragma unroll
            for (int r = 0; r < 4; ++r) {
              const int b_ = mt*16 + 4*q + r;
              lmax[wave*32 + b_] = mv[r]; lsum[wave*32 + b_] = sv[r]; lidx[wave*32 + b_] = mi[r];
            }
          }
        }
        __syncthreads();
        if (tid < 32) {
          float M = lmax[tid], S = lsum[tid]; int I = lidx[tid];
#pragma unroll
          for (int w = 1; w < 4; ++w) comb3(M, S, I, lmax[w*32+tid], lsum[w*32+tid], lidx[w*32+tid]);
          p.pmax[tile*32 + tid] = M; p.psum[tile*32 + tid] = S; p.pidx[tile*32 + tid] = I;
        }
        __syncthreads();
      }
    }
    gg.sync();
  }
  // ---------- final reduce for t=127 ----------
  if (blk < 32) {
    float* red = scr;
    float M = -3.4e38f, S = 0.f; int I = 0x7fffffff;
    for (int tl = tid; tl < 500; tl += 256)
      comb3(M, S, I, p.pmax[tl*32 + blk], p.psum[tl*32 + blk], p.pidx[tl*32 + blk]);
#pragma unroll
    for (int m = 1; m < 64; m <<= 1) {
      const float m2 = __shfl_xor(M, m), s2 = __shfl_xor(S, m);
      const int i2 = __shfl_xor(I, m);
      comb3(M, S, I, m2, s2, i2);
    }
    if (lane == 0) { red[wave] = M; red[4+wave] = S; ((int*)(red+8))[wave] = I; }
    __syncthreads();
    if (tid == 0) {
      M = red[0]; S = red[4]; I = ((int*)(red+8))[0];
      for (int w = 1; w < 4; ++w) comb3(M, S, I, red[w], red[4+w], ((int*)(red+8))[w]);
      atomicAdd(p.loss, (M + __logf(S) - p.ptgt[blk]) * (1.0f/32.0f));
    }
  }
  gg.sync();
  if (blk == 0 && tid == 0) {
    const float l = __hip_atomic_load(p.loss, __ATOMIC_RELAXED, __HIP_MEMORY_SCOPE_AGENT);
    p.out[0] = l;
    p.out[1] = l * (1.0f/128.0f);
  }
}

// =====================================================================
// Fallback path (round-1 multi-kernel, fp32 weights) — used only if the
// cooperative launch is rejected by the runtime/graph capture.
// =====================================================================
__global__ __launch_bounds__(256) void k_init(float* __restrict__ ws,
                                              int* __restrict__ inp,
                                              float* __restrict__ loss)
{
  int gid = blockIdx.x*256 + threadIdx.x;
  if (gid < 131072) ws[gid] = 0.f;
  if (gid < 32) inp[gid] = SOS_;
  if (gid == 0) *loss = 0.f;
}

__global__ __launch_bounds__(256) void k_enc_gates(
    const int* __restrict__ x, int t, const float* __restrict__ emb_enc,
    const float* __restrict__ Wih_f, const float* __restrict__ Whh_f,
    const float* __restrict__ Wih_b, const float* __restrict__ Whh_b,
    const float* __restrict__ hf, const float* __restrict__ hb,
    float* __restrict__ gparts)
{
  const int tid = threadIdx.x;
  const int wave = tid >> 6, lane = tid & 63;
  const int q = lane >> 4, col = lane & 15, kq = q*8;
  const int nt = blockIdx.x, ks = blockIdx.y, dir = blockIdx.z;
  const int n = nt*64 + wave*16 + col;
  const bool inE = (ks < 2);
  const int kbase = ks*256;
  const float* W = inE ? (dir ? Wih_b : Wih_f) : (dir ? Whh_b : Whh_f);
  const int kloc = inE ? kbase : (kbase - 512);
  const float *a0, *a1;
  if (inE) {
    a0 = emb_enc + (size_t)x[col*L_ + t]*E_ + kloc + kq;
    a1 = emb_enc + (size_t)x[(16+col)*L_ + t]*E_ + kloc + kq;
  } else {
    const float* hs = dir ? hb : hf;
    a0 = hs + col*H_ + kloc + kq;
    a1 = hs + (16+col)*H_ + kloc + kq;
  }
  const float* bp = W + (size_t)n*512 + kloc + kq;
  f4 acc0 = {0.f,0.f,0.f,0.f}, acc1 = {0.f,0.f,0.f,0.f};
#pragma unroll
  for (int i = 0; i < 8; ++i) {
    bf8 bb  = fragf(bp + i*32);
    acc0 = mfma16(fragf(a0 + i*32), bb, acc0);
    acc1 = mfma16(fragf(a1 + i*32), bb, acc1);
  }
  float* out = gparts + (size_t)((ks*2 + dir)*B_)*2048;
#pragma unroll
  for (int r = 0; r < 4; ++r) {
    out[(size_t)(4*q + r)*2048 + n]      = acc0[r];
    out[(size_t)(16 + 4*q + r)*2048 + n] = acc1[r];
  }
}

__global__ __launch_bounds__(256) void k_enc_cell(
    const float* __restrict__ gparts,
    const float* __restrict__ bih_f, const float* __restrict__ bhh_f,
    const float* __restrict__ bih_b, const float* __restrict__ bhh_b,
    float* __restrict__ hf, float* __restrict__ cf,
    float* __restrict__ hb, float* __restrict__ cb,
    float* __restrict__ EO, int t)
{
  int gid = blockIdx.x*256 + threadIdx.x;
  int dir = gid >> 14, b = (gid >> 9) & 31, j = gid & 511;
  const float* bi = dir ? bih_b : bih_f;
  const float* bh = dir ? bhh_b : bhh_f;
  float g[4];
#pragma unroll
  for (int gt = 0; gt < 4; ++gt) {
    int n = gt*H_ + j;
    float s = bi[n] + bh[n];
#pragma unroll
    for (int ks = 0; ks < 4; ++ks)
      s += gparts[(size_t)((ks*2 + dir)*B_ + b)*2048 + n];
    g[gt] = s;
  }
  float* c = dir ? cb : cf;
  float* h = dir ? hb : hf;
  float cp = c[b*H_ + j];
  float cn = sigf(g[1])*cp + sigf(g[0])*tanh_(g[2]);
  float hn = sigf(g[3])*tanh_(cn);
  c[b*H_ + j] = cn;
  h[b*H_ + j] = hn;
  if (b == 0) EO[t*H2_ + dir*H_ + j] = hn;
}

__global__ __launch_bounds__(256) void k_attn(
    const int* __restrict__ inp, const float* __restrict__ emb_dec,
    const float* __restrict__ h_d, const float* __restrict__ W_attn,
    const float* __restrict__ b_attn, const float* __restrict__ EO,
    float* __restrict__ ctx)
{
  __shared__ float X[2048];
  __shared__ float sc[128];
  __shared__ float red[8];
  const int b = blockIdx.x, tid = threadIdx.x;
  const int row = inp[b];
  ((f4*)X)[tid]          = ((const f4*)(emb_dec + (size_t)row*H2_))[tid];
  ((f4*)(X + 1024))[tid] = ((const f4*)(h_d + (size_t)b*H2_))[tid];
  __syncthreads();
  const int lg = tid >> 4, kl = tid & 15;
#pragma unroll
  for (int lr = 0; lr < 8; ++lr) {
    const int l = lr*16 + lg;
    const float* w = W_attn + (size_t)l*2048;
    float s = 0.f;
    for (int kk = kl*4; kk < 2048; kk += 64) {
      f4 wv = *(const f4*)(w + kk);
      f4 xv = *(const f4*)(X + kk);
      s += wv[0]*xv[0] + wv[1]*xv[1] + wv[2]*xv[2] + wv[3]*xv[3];
    }
#pragma unroll
    for (int msk = 1; msk < 16; msk <<= 1) s += __shfl_xor(s, msk);
    if (kl == 0) sc[l] = s + b_attn[l];
  }
  __syncthreads();
  const float v = sc[tid & 127];
  float m_ = v;
#pragma unroll
  for (int msk = 1; msk < 64; msk <<= 1) m_ = fmaxf(m_, __shfl_xor(m_, msk));
  if ((tid & 63) == 0) red[tid >> 6] = m_;
  __syncthreads();
  const float M = fmaxf(fmaxf(red[0], red[1]), fmaxf(red[2], red[3]));
  const float e_ = __expf(v - M);
  float s_ = e_;
#pragma unroll
  for (int msk = 1; msk < 64; msk <<= 1) s_ += __shfl_xor(s_, msk);
  if ((tid & 63) == 0) red[4 + (tid >> 6)] = s_;
  __syncthreads();
  const float S = red[4] + red[5];
  if (tid < 128) sc[tid] = e_ / S;
  __syncthreads();
  const int d0 = tid*4;
  f4 a = {0.f,0.f,0.f,0.f};
  for (int l = 0; l < 128; ++l) {
    const float wgt = sc[l];
    const f4 ev = *(const f4*)(EO + (size_t)l*H2_ + d0);
    a[0] += wgt*ev[0]; a[1] += wgt*ev[1]; a[2] += wgt*ev[2]; a[3] += wgt*ev[3];
  }
  *(f4*)(ctx + (size_t)b*H2_ + d0) = a;
}

__global__ __launch_bounds__(256) void k_comb(
    const int* __restrict__ inp, const float* __restrict__ emb_dec,
    const float* __restrict__ ctx, const float* __restrict__ W_comb,
    float* __restrict__ cparts)
{
  const int tid = threadIdx.x, wave = tid>>6, lane = tid&63;
  const int q = lane>>4, col = lane&15, kq = q*8;
  const int nt = blockIdx.x, ks = blockIdx.y;
  const int n = nt*64 + wave*16 + col;
  const int kbase = ks*512;
  const bool inE = (ks < 2);
  const float *a0, *a1;
  if (inE) {
    a0 = emb_dec + (size_t)inp[col]*H2_ + kbase + kq;
    a1 = emb_dec + (size_t)inp[16+col]*H2_ + kbase + kq;
  } else {
    a0 = ctx + col*H2_ + (kbase - 1024) + kq;
    a1 = ctx + (16+col)*H2_ + (kbase - 1024) + kq;
  }
  const float* bp = W_comb + (size_t)n*2048 + kbase + kq;
  f4 acc0={0.f,0.f,0.f,0.f}, acc1={0.f,0.f,0.f,0.f};
#pragma unroll
  for (int i = 0; i < 16; ++i) {
    bf8 bb  = fragf(bp + i*32);
    acc0 = mfma16(fragf(a0 + i*32), bb, acc0);
    acc1 = mfma16(fragf(a1 + i*32), bb, acc1);
  }
  float* out = cparts + (size_t)(ks*B_)*H2_;
#pragma unroll
  for (int r = 0; r < 4; ++r) {
    out[(size_t)(4*q+r)*H2_ + n]    = acc0[r];
    out[(size_t)(16+4*q+r)*H2_ + n] = acc1[r];
  }
}

__device__ __forceinline__ bf8 frag_comb(const float* cp, const float* bias){
  f4 s0 = ((const f4*)cp)[0];
  f4 s1 = ((const f4*)cp)[1];
#pragma unroll
  for (int pq = 1; pq < 4; ++pq) {
    s0 += ((const f4*)(cp + pq*(B_*H2_)))[0];
    s1 += ((const f4*)(cp + pq*(B_*H2_)))[1];
  }
  s0 += ((const f4*)bias)[0];
  s1 += ((const f4*)bias)[1];
  bf8 r;
  r[0]=bf1(fmaxf(s0[0],0.f)); r[1]=bf1(fmaxf(s0[1],0.f));
  r[2]=bf1(fmaxf(s0[2],0.f)); r[3]=bf1(fmaxf(s0[3],0.f));
  r[4]=bf1(fmaxf(s1[0],0.f)); r[5]=bf1(fmaxf(s1[1],0.f));
  r[6]=bf1(fmaxf(s1[2],0.f)); r[7]=bf1(fmaxf(s1[3],0.f));
  return r;
}

__global__ __launch_bounds__(256) void k_dec_gates(
    const float* __restrict__ cparts, const float* __restrict__ b_comb,
    const float* __restrict__ h_d,
    const float* __restrict__ Wih_d, const float* __restrict__ Whh_d,
    float* __restrict__ gparts)
{
  const int tid = threadIdx.x, wave = tid>>6, lane = tid&63;
  const int q = lane>>4, col = lane&15, kq = q*8;
  const int nt = blockIdx.x, ks = blockIdx.y;
  const int n = nt*64 + wave*16 + col;
  const int kbase = ks*512;
  const bool inC = (ks < 2);
  f4 acc0={0.f,0.f,0.f,0.f}, acc1={0.f,0.f,0.f,0.f};
  if (inC) {
    const float* c0 = cparts + col*H2_ + kbase + kq;
    const float* c1 = cparts + (16+col)*H2_ + kbase + kq;
    const float* bp = Wih_d + (size_t)n*H2_ + kbase + kq;
    const float* bsp = b_comb + kbase + kq;
#pragma unroll
    for (int i = 0; i < 16; ++i) {
      bf8 bb  = fragf(bp + i*32);
      acc0 = mfma16(frag_comb(c0 + i*32, bsp + i*32), bb, acc0);
      acc1 = mfma16(frag_comb(c1 + i*32, bsp + i*32), bb, acc1);
    }
  } else {
    const int kh = kbase - 1024;
    const float* a0 = h_d + col*H2_ + kh + kq;
    const float* a1 = h_d + (16+col)*H2_ + kh + kq;
    const float* bp = Whh_d + (size_t)n*H2_ + kh + kq;
#pragma unroll
    for (int i = 0; i < 16; ++i) {
      bf8 bb  = fragf(bp + i*32);
      acc0 = mfma16(fragf(a0 + i*32), bb, acc0);
      acc1 = mfma16(fragf(a1 + i*32), bb, acc1);
    }
  }
  float* out = gparts + (size_t)(ks*B_)*4096;
#pragma unroll
  for (int r = 0; r < 4; ++r) {
    out[(size_t)(4*q+r)*4096 + n]    = acc0[r];
    out[(size_t)(16+4*q+r)*4096 + n] = acc1[r];
  }
}

__global__ __launch_bounds__(256) void k_dec_cell(
    const float* __restrict__ gparts, const float* __restrict__ bih_d,
    const float* __restrict__ bhh_d, float* __restrict__ h_d,
    float* __restrict__ c_d)
{
  int gid = blockIdx.x*256 + threadIdx.x;
  int b = gid >> 10, j = gid & 1023;
  float g[4];
#pragma unroll
  for (int gt = 0; gt < 4; ++gt) {
    int n = gt*H2_ + j;
    float s = bih_d[n] + bhh_d[n];
#pragma unroll
    for (int ks = 0; ks < 4; ++ks)
      s += gparts[(size_t)(ks*B_ + b)*4096 + n];
    g[gt] = s;
  }
  float cp = c_d[b*H2_ + j];
  float cn = sigf(g[1])*cp + sigf(g[0])*tanh_(g[2]);
  float hn = sigf(g[3])*tanh_(cn);
  c_d[b*H2_ + j] = cn;
  h_d[b*H2_ + j] = hn;
}

__global__ __launch_bounds__(256) void k_logits_f(
    const float* __restrict__ h_d,
    const float* __restrict__ W_out, const float* __restrict__ b_out,
    const int* __restrict__ target, int t,
    float* __restrict__ pmax, float* __restrict__ psum,
    int* __restrict__ pidx, float* __restrict__ ptgt)
{
  __shared__ float lmax[4][32], lsum[4][32];
  __shared__ int lidx[4][32];
  const int tid = threadIdx.x, wave = tid>>6, lane = tid&63;
  const int q = lane>>4, col = lane&15, kq = q*8;
  const int nt = blockIdx.x;
  const int n = nt*64 + wave*16 + col;
  const float* a0 = h_d + col*H2_ + kq;
  const float* a1 = h_d + (16+col)*H2_ + kq;
  f4 acc[2];
  acc[0] = (f4){0.f,0.f,0.f,0.f};
  acc[1] = (f4){0.f,0.f,0.f,0.f};
  const float* bp = W_out + (size_t)n*H2_ + kq;
#pragma unroll 4
  for (int i = 0; i < 32; ++i) {
    bf8 bb = fragf(bp + i*32);
    acc[0] = mfma16(fragf(a0 + i*32), bb, acc[0]);
    acc[1] = mfma16(fragf(a1 + i*32), bb, acc[1]);
  }
  const float bias = b_out[n];
#pragma unroll
  for (int mt = 0; mt < 2; ++mt) {
    float val[4], mv[4]; int mi[4];
#pragma unroll
    for (int r = 0; r < 4; ++r) {
      val[r] = acc[mt][r] + bias;
      int b_ = mt*16 + 4*q + r;
      if (target[b_*L_ + t] == n) ptgt[b_] = val[r];
      mv[r] = val[r]; mi[r] = n;
    }
#pragma unroll
    for (int msk = 1; msk < 16; msk <<= 1) {
#pragma unroll
      for (int r = 0; r < 4; ++r) {
        float ov = __shfl_xor(mv[r], msk);
        int oi = __shfl_xor(mi[r], msk);
        if (ov > mv[r] || (ov == mv[r] && oi < mi[r])) { mv[r] = ov; mi[r] = oi; }
      }
    }
    float sv[4];
#pragma unroll
    for (int r = 0; r < 4; ++r) sv[r] = __expf(val[r] - mv[r]);
#pragma unroll
    for (int msk = 1; msk < 16; msk <<= 1) {
#pragma unroll
      for (int r = 0; r < 4; ++r) sv[r] += __shfl_xor(sv[r], msk);
    }
    if (col == 0) {
#pragma unroll
      for (int r = 0; r < 4; ++r) {
        int b_ = mt*16 + 4*q + r;
        lmax[wave][b_] = mv[r]; lsum[wave][b_] = sv[r]; lidx[wave][b_] = mi[r];
      }
    }
  }
  __syncthreads();
  if (tid < 32) {
    float M = lmax[0][tid], S = lsum[0][tid]; int I = lidx[0][tid];
#pragma unroll
    for (int w = 1; w < 4; ++w) comb3(M, S, I, lmax[w][tid], lsum[w][tid], lidx[w][tid]);
    pmax[nt*32 + tid] = M; psum[nt*32 + tid] = S; pidx[nt*32 + tid] = I;
  }
}

__global__ __launch_bounds__(256) void k_reduce(
    const float* __restrict__ pmax, const float* __restrict__ psum,
    const int* __restrict__ pidx, const float* __restrict__ ptgt,
    float* __restrict__ loss, int* __restrict__ inp)
{
  __shared__ float sm[4], ss[4]; __shared__ int si[4];
  const int b = blockIdx.x, tid = threadIdx.x;
  float M = -3.4e38f, S = 0.f; int I = 0x7fffffff;
  for (int tl = tid; tl < 500; tl += 256)
    comb3(M, S, I, pmax[tl*32 + b], psum[tl*32 + b], pidx[tl*32 + b]);
#pragma unroll
  for (int msk = 1; msk < 64; msk <<= 1) {
    float m2 = __shfl_xor(M, msk), s2 = __shfl_xor(S, msk);
    int i2 = __shfl_xor(I, msk);
    comb3(M, S, I, m2, s2, i2);
  }
  if ((tid & 63) == 0) { sm[tid>>6] = M; ss[tid>>6] = S; si[tid>>6] = I; }
  __syncthreads();
  if (tid == 0) {
    M = sm[0]; S = ss[0]; I = si[0];
    for (int w = 1; w < 4; ++w) comb3(M, S, I, sm[w], ss[w], si[w]);
    atomicAdd(loss, (M + __logf(S) - ptgt[b]) * (1.0f/32.0f));
    inp[b] = I;
  }
}

__global__ void k_final(const float* __restrict__ loss, float* __restrict__ out)
{
  out[0] = *loss;
  out[1] = *loss * (1.0f/128.0f);
}

// ---------------- host ----------------
extern "C" void kernel_launch(void* const* d_in, const int* in_sizes, int n_in,
                              void* d_out, int out_size, void* d_ws, size_t ws_size,
                              hipStream_t stream)
{
  const int*   x       = (const int*)d_in[0];
  const int*   target  = (const int*)d_in[1];
  const float* emb_enc = (const float*)d_in[4];
  const float* Wih_f   = (const float*)d_in[5];
  const float* Whh_f   = (const float*)d_in[6];
  const float* bih_f   = (const float*)d_in[7];
  const float* bhh_f   = (const float*)d_in[8];
  const float* Wih_b   = (const float*)d_in[9];
  const float* Whh_b   = (const float*)d_in[10];
  const float* bih_b   = (const float*)d_in[11];
  const float* bhh_b   = (const float*)d_in[12];
  const float* emb_dec = (const float*)d_in[13];
  const float* W_attn  = (const float*)d_in[14];
  const float* b_attn  = (const float*)d_in[15];
  const float* W_comb  = (const float*)d_in[16];
  const float* b_comb  = (const float*)d_in[17];
  const float* Wih_d   = (const float*)d_in[18];
  const float* Whh_d   = (const float*)d_in[19];
  const float* bih_d   = (const float*)d_in[20];
  const float* bhh_d   = (const float*)d_in[21];
  const float* W_out   = (const float*)d_in[22];
  const float* b_out   = (const float*)d_in[23];

  char* wsb = (char*)d_ws;
  MP prm;
  prm.x = x; prm.target = target;
  prm.emb_enc = emb_enc;
  prm.Wih_f = Wih_f; prm.Whh_f = Whh_f; prm.bih_f = bih_f; prm.bhh_f = bhh_f;
  prm.Wih_b = Wih_b; prm.Whh_b = Whh_b; prm.bih_b = bih_b; prm.bhh_b = bhh_b;
  prm.emb_dec = emb_dec; prm.W_attn = W_attn; prm.b_attn = b_attn;
  prm.W_comb = W_comb; prm.b_comb = b_comb;
  prm.Wih_d = Wih_d; prm.Whh_d = Whh_d; prm.bih_d = bih_d; prm.bhh_d = bhh_d;
  prm.W_out = W_out; prm.b_out = b_out;
  prm.h_enc = (unsigned short*)(wsb + 0);
  prm.h_d   = (unsigned short*)(wsb + 131072);
  prm.EO    = (float*)(wsb + 196608);
  prm.ctxb  = (unsigned short*)(wsb + 720896);
  prm.comb  = (unsigned short*)(wsb + 786432);
  prm.pmax  = (float*)(wsb + 851968);
  prm.psum  = (float*)(wsb + 915968);
  prm.pidx  = (int*)(wsb + 979968);
  prm.ptgt  = (float*)(wsb + 1043968);
  prm.loss  = (float*)(wsb + 1044096);
  prm.inp   = (int*)(wsb + 1044352);
  prm.benc  = (float*)(wsb + 1044480);
  prm.bdec  = (float*)(wsb + 1060864);
  prm.Wencb = (unsigned short*)(wsb + 1077248);
  prm.Whhdb = (unsigned short*)(wsb + 9465856);
  prm.Wihdb = (unsigned short*)(wsb + 17854464);
  prm.Wcombb= (unsigned short*)(wsb + 26243072);
  prm.Woutb = (unsigned short*)(wsb + 30437376);
  prm.out   = (float*)d_out;

  const size_t NEED = 95973376ull;
  const bool pk = (ws_size >= NEED);
  void* args[] = { &prm };
  hipError_t rc;
  if (pk)
    rc = hipLaunchCooperativeKernel(reinterpret_cast<const void*>(&mega<true>),
                                    dim3(NBLK), dim3(256), args, 0, stream);
  else
    rc = hipLaunchCooperativeKernel(reinterpret_cast<const void*>(&mega<false>),
                                    dim3(NBLK), dim3(256), args, 0, stream);
  if (rc == hipSuccess) return;
  (void)hipGetLastError();   // clear error state, run fallback

  // ---------- fallback: round-1 multi-kernel path ----------
  float* ws    = (float*)d_ws;
  float* hf    = ws + 0;
  float* cf    = ws + 16384;
  float* hb    = ws + 32768;
  float* cb    = ws + 49152;
  float* h_d   = ws + 65536;
  float* c_d   = ws + 98304;
  float* EO    = ws + 131072;
  float* ctx   = ws + 262144;
  float* cparts= ws + 294912;
  float* gpe   = ws + 425984;
  float* gpd   = ws + 950272;
  float* pmax  = ws + 1474560;
  float* psum  = ws + 1490560;
  int*   pidx  = (int*)(ws + 1506560);
  float* ptgt  = ws + 1522560;
  float* loss  = ws + 1522592;
  int*   inp   = (int*)(ws + 1522624);
  float* out   = (float*)d_out;

  k_init<<<512, 256, 0, stream>>>(ws, inp, loss);
  for (int t = 0; t < L_; ++t) {
    k_enc_gates<<<dim3(32,4,2), 256, 0, stream>>>(
        x, t, emb_enc, Wih_f, Whh_f, Wih_b, Whh_b, hf, hb, gpe);
    k_enc_cell<<<128, 256, 0, stream>>>(
        gpe, bih_f, bhh_f, bih_b, bhh_b, hf, cf, hb, cb, EO, t);
  }
  for (int t = 0; t < L_; ++t) {
    k_attn<<<32, 256, 0, stream>>>(inp, emb_dec, h_d, W_attn, b_attn, EO, ctx);
    k_comb<<<dim3(16,4), 256, 0, stream>>>(inp, emb_dec, ctx, W_comb, cparts);
    k_dec_gates<<<dim3(64,4), 256, 0, stream>>>(
        cparts, b_comb, h_d, Wih_d, Whh_d, gpd);
    k_dec_cell<<<128, 256, 0, stream>>>(gpd, bih_d, bhh_d, h_d, c_d);
    k_logits_f<<<500, 256, 0, stream>>>(
        h_d, W_out, b_out, target, t, pmax, psum, pidx, ptgt);
    k_reduce<<<32, 256, 0, stream>>>(pmax, psum, pidx, ptgt, loss, inp);
  }
  k_final<<<1, 1, 0, stream>>>(loss, out);
}